// Round 1
// 686.447 us; speedup vs baseline: 1.0322x; 1.0322x over previous
//
#include <hip/hip_runtime.h>

#define NN 50000
#define EE 800000

// ---------------- bf16 helpers ----------------
__device__ inline unsigned int bf_pack(float lo, float hi) {
  unsigned int a = __float_as_uint(lo);
  a += 0x7FFFu + ((a >> 16) & 1u);
  unsigned int b = __float_as_uint(hi);
  b += 0x7FFFu + ((b >> 16) & 1u);
  return (a >> 16) | ((b >> 16) << 16);
}
__device__ inline void bf_dec8(uint4 v, float* f) {
  f[0] = __uint_as_float(v.x << 16); f[1] = __uint_as_float(v.x & 0xFFFF0000u);
  f[2] = __uint_as_float(v.y << 16); f[3] = __uint_as_float(v.y & 0xFFFF0000u);
  f[4] = __uint_as_float(v.z << 16); f[5] = __uint_as_float(v.z & 0xFFFF0000u);
  f[6] = __uint_as_float(v.w << 16); f[7] = __uint_as_float(v.w & 0xFFFF0000u);
}
__device__ inline float lrelu(float v) { return v >= 0.f ? v : 0.2f * v; }

// ================= CSR build =================
__global__ __launch_bounds__(256) void deg2_k(
    const int* __restrict__ dst0, const int* __restrict__ dst1,
    int* __restrict__ deg) {
  int i = blockIdx.x * 256 + threadIdx.x;
  if (i < EE) atomicAdd(&deg[dst0[i]], 1);
  else if (i < 2 * EE) atomicAdd(&deg[50000 + dst1[i - EE]], 1);
}

__global__ __launch_bounds__(512) void scan1_k(const int* __restrict__ deg,
                                               int* __restrict__ inc,
                                               int* __restrict__ bsum) {
  __shared__ int s[512];
  int e = blockIdx.y;
  int t = threadIdx.x, i = blockIdx.x * 512 + t;
  int v = (i < NN) ? deg[e * 50000 + i] : 0;
  s[t] = v; __syncthreads();
  #pragma unroll
  for (int off = 1; off < 512; off <<= 1) {
    int u = (t >= off) ? s[t - off] : 0;
    __syncthreads();
    s[t] += u;
    __syncthreads();
  }
  if (i < NN) inc[e * 50000 + i] = s[t];
  if (t == 511) bsum[e * 128 + blockIdx.x] = s[511];
}

__global__ __launch_bounds__(128) void scan2_k(int* __restrict__ bsum, int nb) {
  __shared__ int s[128];
  int e = blockIdx.x;
  int t = threadIdx.x;
  int v = (t < nb) ? bsum[e * 128 + t] : 0;
  s[t] = v; __syncthreads();
  #pragma unroll
  for (int off = 1; off < 128; off <<= 1) {
    int u = (t >= off) ? s[t - off] : 0;
    __syncthreads();
    s[t] += u;
    __syncthreads();
  }
  if (t < nb) bsum[e * 128 + t] = s[t] - v;
}

// rowptr + cursor init (cursor = rowptr copy so scatter atomics return
// absolute indices directly — removes one random read per edge).
__global__ __launch_bounds__(256) void scan3_k(const int* __restrict__ deg,
                                               const int* __restrict__ inc,
                                               const int* __restrict__ bsum,
                                               int* __restrict__ rowptr,
                                               int* __restrict__ cursor) {
  int e = blockIdx.y;
  int i = blockIdx.x * 256 + threadIdx.x;
  if (i < NN) {
    int v = inc[e * 50000 + i] - deg[e * 50000 + i] + bsum[e * 128 + (i >> 9)];
    rowptr[e * 50001 + i] = v;
    cursor[e * 50000 + i] = v;
  }
  if (i == NN) rowptr[e * 50001 + NN] = EE;
}

// XCD-partitioned scatter: blocks with (blockIdx.x & 7)==r own dst range
// [r*6250, (r+1)*6250). Round-robin block->XCD dispatch confines each XCD's
// random writes to ~800 KB of csr_src + 50 KB of cursor (both L2-resident),
// collapsing the ~17x HBM write amplification of the unpartitioned scatter.
// Edge list is streamed 8x but is L3-resident (12.8 MB).
#define SC_BPR 256  // blocks per range; grid = 8 * SC_BPR
__global__ __launch_bounds__(256) void csr_scatter2_k(
    const int* __restrict__ src0, const int* __restrict__ dst0,
    const int* __restrict__ src1, const int* __restrict__ dst1,
    int* __restrict__ cursor, int* __restrict__ csr_src) {
  const int range = blockIdx.x & 7;
  const int bpr = blockIdx.x >> 3;
  const int lo = range * 6250;
  const int hi = lo + 6250;
  #pragma unroll
  for (int e = 0; e < 2; e++) {
    const int* ds = e ? dst1 : dst0;
    const int* ss = e ? src1 : src0;
    int* cur = cursor + e * 50000;
    int* outp = csr_src + (size_t)e * EE;
    for (int i = bpr * 256 + threadIdx.x; i < EE; i += SC_BPR * 256) {
      int d = ds[i];
      if (d >= lo && d < hi) {
        int pos = atomicAdd(&cur[d], 1);
        outp[pos] = ss[i];
      }
    }
  }
}

// ======== fold a_l/a_r through weights ========
__global__ __launch_bounds__(256) void fold_k(
    const float* __restrict__ W1, const float* __restrict__ al1, const float* __restrict__ ar1,
    const float* __restrict__ W2, const float* __restrict__ al2, const float* __restrict__ ar2,
    const float* __restrict__ Wm, const float* __restrict__ alm, const float* __restrict__ arm,
    float* __restrict__ wl1, float* __restrict__ wr1,
    float* __restrict__ wl2, float* __restrict__ wr2,
    float* __restrict__ wlm, float* __restrict__ wrm) {
  int t = blockIdx.x * 256 + threadIdx.x;
  if (t < 512) {
    int lr = t >> 8, e = (t >> 7) & 1, k = t & 127;
    const float* a = (lr ? ar1 : al1) + e * 128;
    const float* w = W1 + ((size_t)e * 128 + k) * 128;
    float s = 0.f;
    for (int f = 0; f < 128; f++) s += w[f] * a[f];
    (lr ? wr1 : wl1)[e * 128 + k] = s;
  } else if (t < 1024) {
    int u = t - 512;
    int lr = u >> 8, e = (u >> 7) & 1, k = u & 127;
    const float* a = (lr ? ar2 : al2) + e * 64;
    const float* w = W2 + ((size_t)e * 128 + k) * 64;
    float s = 0.f;
    for (int f = 0; f < 64; f++) s += w[f] * a[f];
    (lr ? wr2 : wl2)[e * 128 + k] = s;
  } else if (t < 2048) {
    int u = t - 1024;
    int lr = u >> 9, e = (u >> 8) & 1, h = (u >> 6) & 3, k = u & 63;
    const float* a = (lr ? arm : alm) + (e * 4 + h) * 64;
    const float* w = Wm + ((size_t)e * 64 + k) * 256 + h * 64;
    float s = 0.f;
    for (int f = 0; f < 64; f++) s += w[f] * a[f];
    (lr ? wrm : wlm)[(e * 4 + h) * 64 + k] = s;
  }
}

// ======== cast x to bf16 ========
__global__ __launch_bounds__(256) void xcast_k(const float* __restrict__ x,
                                               unsigned int* __restrict__ xb) {
  int i = blockIdx.x * 256 + threadIdx.x;
  if (i >= NN * 64) return;
  float2 v = *(const float2*)(x + (size_t)i * 2);
  xb[i] = bf_pack(v.x, v.y);
}

// ================= el/er dots (fp32 features, K=128, both etypes) =============
__global__ __launch_bounds__(256) void dot2_k(
    const float* __restrict__ X, const float* __restrict__ wl,
    const float* __restrict__ wr, float* __restrict__ el, float* __restrict__ er) {
  int n = blockIdx.x * 16 + (threadIdx.x >> 4);
  int lane = threadIdx.x & 15;
  if (n >= NN) return;
  float p[4] = {0.f, 0.f, 0.f, 0.f};
  #pragma unroll
  for (int i = 0; i < 2; i++) {
    int c = (lane + i * 16) * 4;
    float4 xv = *(const float4*)(X + (size_t)n * 128 + c);
    #pragma unroll
    for (int e = 0; e < 2; e++) {
      float4 a = *(const float4*)(wl + e * 128 + c);
      float4 b = *(const float4*)(wr + e * 128 + c);
      p[e*2+0] += xv.x*a.x + xv.y*a.y + xv.z*a.z + xv.w*a.w;
      p[e*2+1] += xv.x*b.x + xv.y*b.y + xv.z*b.z + xv.w*b.w;
    }
  }
  #pragma unroll
  for (int off = 1; off < 16; off <<= 1) {
    #pragma unroll
    for (int i = 0; i < 4; i++) p[i] += __shfl_xor(p[i], off);
  }
  if (lane == 0) {
    el[n] = p[0]; er[n] = p[1];
    el[NN + n] = p[2]; er[NN + n] = p[3];
  }
}

// ===== layer1: fused alpha + gather of bf16 x; u1[e][d][128] =====
__global__ __launch_bounds__(256) void agg_x_f(
    const int* __restrict__ rowptr, const int* __restrict__ csr_src,
    const float* __restrict__ el, const float* __restrict__ er,
    const uint4* __restrict__ xb, float* __restrict__ u1) {
  int d = blockIdx.x * 16 + (threadIdx.x >> 4);
  int lane = threadIdx.x & 15;
  if (d >= NN) return;
  #pragma unroll
  for (int e = 0; e < 2; e++) {
    const int* rp = rowptr + e * 50001;
    const int* cs = csr_src + (size_t)e * EE;
    const float* elp = el + (size_t)e * NN;
    float erd = er[(size_t)e * NN + d];
    int j0 = rp[d], j1 = rp[d + 1];
    float sm = 0.f;
    for (int j = j0 + lane; j < j1; j += 16) {
      float v = elp[cs[j]] + erd; v = v >= 0.f ? v : 0.2f * v;
      sm += __expf(v);
    }
    #pragma unroll
    for (int off = 1; off < 16; off <<= 1) sm += __shfl_xor(sm, off, 16);
    float inv = 1.f / fmaxf(sm, 1e-9f);
    float acc[8] = {};
    int j = j0;
    for (; j + 4 <= j1; j += 4) {
      int s0 = cs[j], s1 = cs[j+1], s2 = cs[j+2], s3 = cs[j+3];
      float e0 = elp[s0] + erd; e0 = e0 >= 0.f ? e0 : 0.2f*e0;
      float e1 = elp[s1] + erd; e1 = e1 >= 0.f ? e1 : 0.2f*e1;
      float e2 = elp[s2] + erd; e2 = e2 >= 0.f ? e2 : 0.2f*e2;
      float e3 = elp[s3] + erd; e3 = e3 >= 0.f ? e3 : 0.2f*e3;
      uint4 v0 = xb[(size_t)s0 * 16 + lane];
      uint4 v1 = xb[(size_t)s1 * 16 + lane];
      uint4 v2 = xb[(size_t)s2 * 16 + lane];
      uint4 v3 = xb[(size_t)s3 * 16 + lane];
      float a0 = __expf(e0) * inv, a1 = __expf(e1) * inv;
      float a2 = __expf(e2) * inv, a3 = __expf(e3) * inv;
      float f0[8], f1[8], f2[8], f3[8];
      bf_dec8(v0, f0); bf_dec8(v1, f1); bf_dec8(v2, f2); bf_dec8(v3, f3);
      #pragma unroll
      for (int c = 0; c < 8; c++)
        acc[c] += a0*f0[c] + a1*f1[c] + a2*f2[c] + a3*f3[c];
    }
    for (; j < j1; j++) {
      int s = cs[j];
      float v = elp[s] + erd; v = v >= 0.f ? v : 0.2f*v;
      float a = __expf(v) * inv;
      uint4 vv = xb[(size_t)s * 16 + lane];
      float f[8]; bf_dec8(vv, f);
      #pragma unroll
      for (int c = 0; c < 8; c++) acc[c] += a * f[c];
    }
    float* up = u1 + ((size_t)e * NN + d) * 128 + lane * 8;
    *(float4*)up       = make_float4(acc[0], acc[1], acc[2], acc[3]);
    *(float4*)(up + 4) = make_float4(acc[4], acc[5], acc[6], acc[7]);
  }
}

// ===== h1 = 0.5*(u1[0]@W1[0] + u1[1]@W1[1]) + 0.5*(b1[0]+b1[1]) =====
__global__ __launch_bounds__(256) void ugemm1_k(
    const float* __restrict__ u1, const float* __restrict__ W1,
    const float* __restrict__ b1, float* __restrict__ h1) {
  __shared__ float As[16][132];
  __shared__ float Bs[16][132];
  const int tid = threadIdx.x;
  const int tx = tid & 15, ty = tid >> 4;
  const int row0 = blockIdx.x * 128;
  float acc[2][2][16] = {};
  for (int e = 0; e < 2; e++) {
    const float* Up = u1 + (size_t)e * NN * 128;
    const float* Wp = W1 + (size_t)e * 128 * 128;
    for (int k0 = 0; k0 < 128; k0 += 16) {
      #pragma unroll
      for (int i = 0; i < 2; i++) {
        int t = tid + i * 256;
        int r = t >> 2, cv = t & 3;
        int rr = row0 + r; if (rr >= NN) rr = NN - 1;
        float4 v = *(const float4*)(Up + (size_t)rr * 128 + k0 + cv * 4);
        As[cv*4+0][r] = v.x; As[cv*4+1][r] = v.y;
        As[cv*4+2][r] = v.z; As[cv*4+3][r] = v.w;
      }
      #pragma unroll
      for (int i = 0; i < 2; i++) {
        int t = tid + i * 256;
        int r = t >> 5, c = t & 31;
        *(float4*)&Bs[r][c*4] = *(const float4*)(Wp + (size_t)(k0 + r) * 128 + c * 4);
      }
      __syncthreads();
      #pragma unroll
      for (int kk = 0; kk < 16; kk++) {
        float4 a[2], b[2];
        a[0] = *(const float4*)&As[kk][ty*4];
        a[1] = *(const float4*)&As[kk][64 + ty*4];
        b[0] = *(const float4*)&Bs[kk][tx*4];
        b[1] = *(const float4*)&Bs[kk][64 + tx*4];
        #pragma unroll
        for (int rp = 0; rp < 2; rp++) {
          #pragma unroll
          for (int cp = 0; cp < 2; cp++) {
            float* ac = acc[rp][cp];
            float4 av = a[rp], bv = b[cp];
            ac[0]  += av.x*bv.x; ac[1]  += av.x*bv.y; ac[2]  += av.x*bv.z; ac[3]  += av.x*bv.w;
            ac[4]  += av.y*bv.x; ac[5]  += av.y*bv.y; ac[6]  += av.y*bv.z; ac[7]  += av.y*bv.w;
            ac[8]  += av.z*bv.x; ac[9]  += av.z*bv.y; ac[10] += av.z*bv.z; ac[11] += av.z*bv.w;
            ac[12] += av.w*bv.x; ac[13] += av.w*bv.y; ac[14] += av.w*bv.z; ac[15] += av.w*bv.w;
          }
        }
      }
      __syncthreads();
    }
  }
  #pragma unroll
  for (int rp = 0; rp < 2; rp++) {
    #pragma unroll
    for (int cp = 0; cp < 2; cp++) {
      int c = cp * 64 + tx * 4;
      float4 bb = make_float4(0.5f*(b1[c] + b1[128+c]),   0.5f*(b1[c+1] + b1[128+c+1]),
                              0.5f*(b1[c+2] + b1[128+c+2]), 0.5f*(b1[c+3] + b1[128+c+3]));
      #pragma unroll
      for (int i = 0; i < 4; i++) {
        int r = row0 + rp*64 + ty*4 + i;
        if (r < NN) {
          float* ac = acc[rp][cp];
          *(float4*)(h1 + (size_t)r * 128 + c) =
              make_float4(0.5f*ac[i*4+0] + bb.x, 0.5f*ac[i*4+1] + bb.y,
                          0.5f*ac[i*4+2] + bb.z, 0.5f*ac[i*4+3] + bb.w);
        }
      }
    }
  }
}

// ================= z2 (bf16) = h1 @ W2[e], 128x64 tiles ===================
__global__ __launch_bounds__(256) void gemm64_k(
    const float* __restrict__ X, const float* __restrict__ W,
    unsigned int* __restrict__ Zb) {
  __shared__ float As[16][132];
  __shared__ float Bs[16][68];
  const int e = blockIdx.z;
  const float* Wp = W + (size_t)e * 128 * 64;
  const int tid = threadIdx.x;
  const int tx = tid & 15, ty = tid >> 4;
  const int row0 = blockIdx.x * 128;
  float acc[2][16] = {};
  for (int k0 = 0; k0 < 128; k0 += 16) {
    #pragma unroll
    for (int i = 0; i < 2; i++) {
      int t = tid + i * 256;
      int r = t >> 2, cv = t & 3;
      int rr = row0 + r; if (rr >= NN) rr = NN - 1;
      float4 v = *(const float4*)(X + (size_t)rr * 128 + k0 + cv * 4);
      As[cv*4+0][r] = v.x; As[cv*4+1][r] = v.y;
      As[cv*4+2][r] = v.z; As[cv*4+3][r] = v.w;
    }
    {
      int r = tid >> 4, c = tid & 15;
      *(float4*)&Bs[r][c*4] = *(const float4*)(Wp + (size_t)(k0 + r) * 64 + c * 4);
    }
    __syncthreads();
    #pragma unroll
    for (int kk = 0; kk < 16; kk++) {
      float4 a0 = *(const float4*)&As[kk][ty*4];
      float4 a1 = *(const float4*)&As[kk][64 + ty*4];
      float4 bv = *(const float4*)&Bs[kk][tx*4];
      float* ac = acc[0];
      ac[0]  += a0.x*bv.x; ac[1]  += a0.x*bv.y; ac[2]  += a0.x*bv.z; ac[3]  += a0.x*bv.w;
      ac[4]  += a0.y*bv.x; ac[5]  += a0.y*bv.y; ac[6]  += a0.y*bv.z; ac[7]  += a0.y*bv.w;
      ac[8]  += a0.z*bv.x; ac[9]  += a0.z*bv.y; ac[10] += a0.z*bv.z; ac[11] += a0.z*bv.w;
      ac[12] += a0.w*bv.x; ac[13] += a0.w*bv.y; ac[14] += a0.w*bv.z; ac[15] += a0.w*bv.w;
      ac = acc[1];
      ac[0]  += a1.x*bv.x; ac[1]  += a1.x*bv.y; ac[2]  += a1.x*bv.z; ac[3]  += a1.x*bv.w;
      ac[4]  += a1.y*bv.x; ac[5]  += a1.y*bv.y; ac[6]  += a1.y*bv.z; ac[7]  += a1.y*bv.w;
      ac[8]  += a1.z*bv.x; ac[9]  += a1.z*bv.y; ac[10] += a1.z*bv.z; ac[11] += a1.z*bv.w;
      ac[12] += a1.w*bv.x; ac[13] += a1.w*bv.y; ac[14] += a1.w*bv.z; ac[15] += a1.w*bv.w;
    }
    __syncthreads();
  }
  #pragma unroll
  for (int rp = 0; rp < 2; rp++) {
    #pragma unroll
    for (int i = 0; i < 4; i++) {
      int r = row0 + rp*64 + ty*4 + i;
      if (r < NN) {
        float* ac = acc[rp];
        uint2 o;
        o.x = bf_pack(ac[i*4+0], ac[i*4+1]);
        o.y = bf_pack(ac[i*4+2], ac[i*4+3]);
        *(uint2*)(Zb + ((size_t)e * NN + r) * 32 + tx * 2) = o;
      }
    }
  }
}

// ===== layer2: fused alpha + gather bf16 z2 + fc/bias + bf16 h2 + MH dots =====
__global__ __launch_bounds__(256) void agg2_f(
    const int* __restrict__ rowptr, const int* __restrict__ csr_src,
    const float* __restrict__ el, const float* __restrict__ er,
    const uint4* __restrict__ zb, const float* __restrict__ bias,
    const float* __restrict__ fcw, const float* __restrict__ wlm,
    const float* __restrict__ wrm, uint4* __restrict__ h2b,
    float* __restrict__ elm, float* __restrict__ erm) {
  int d = blockIdx.x * 32 + (threadIdx.x >> 3);
  int lane = threadIdx.x & 7;
  if (d >= NN) return;
  int c0 = lane * 8;
  float coef0 = 0.5f * (fcw[0] + fcw[2]);
  float coef1 = 0.5f * (fcw[1] + fcw[3]);
  float hrow[8];
  #pragma unroll
  for (int c = 0; c < 8; c++)
    hrow[c] = coef0 * bias[c0 + c] + coef1 * bias[64 + c0 + c];
  #pragma unroll
  for (int e = 0; e < 2; e++) {
    const int* rp = rowptr + e * 50001;
    const int* cs = csr_src + (size_t)e * EE;
    const float* elp = el + (size_t)e * NN;
    float erd = er[(size_t)e * NN + d];
    const uint4* zp = zb + (size_t)e * NN * 8;
    int j0 = rp[d], j1 = rp[d + 1];
    float sm = 0.f;
    for (int j = j0 + lane; j < j1; j += 8) {
      float v = elp[cs[j]] + erd; v = v >= 0.f ? v : 0.2f * v;
      sm += __expf(v);
    }
    #pragma unroll
    for (int off = 1; off < 8; off <<= 1) sm += __shfl_xor(sm, off, 8);
    float cinv = (e ? coef1 : coef0) / fmaxf(sm, 1e-9f);
    float acc[8] = {};
    int j = j0;
    for (; j + 4 <= j1; j += 4) {
      int s0 = cs[j], s1 = cs[j+1], s2 = cs[j+2], s3 = cs[j+3];
      float e0 = elp[s0] + erd; e0 = e0 >= 0.f ? e0 : 0.2f*e0;
      float e1 = elp[s1] + erd; e1 = e1 >= 0.f ? e1 : 0.2f*e1;
      float e2 = elp[s2] + erd; e2 = e2 >= 0.f ? e2 : 0.2f*e2;
      float e3 = elp[s3] + erd; e3 = e3 >= 0.f ? e3 : 0.2f*e3;
      uint4 v0 = zp[(size_t)s0 * 8 + lane];
      uint4 v1 = zp[(size_t)s1 * 8 + lane];
      uint4 v2 = zp[(size_t)s2 * 8 + lane];
      uint4 v3 = zp[(size_t)s3 * 8 + lane];
      float a0 = __expf(e0), a1 = __expf(e1), a2 = __expf(e2), a3 = __expf(e3);
      float f0[8], f1[8], f2[8], f3[8];
      bf_dec8(v0, f0); bf_dec8(v1, f1); bf_dec8(v2, f2); bf_dec8(v3, f3);
      #pragma unroll
      for (int c = 0; c < 8; c++)
        acc[c] += a0*f0[c] + a1*f1[c] + a2*f2[c] + a3*f3[c];
    }
    for (; j < j1; j++) {
      int s = cs[j];
      float v = elp[s] + erd; v = v >= 0.f ? v : 0.2f*v;
      float a = __expf(v);
      uint4 vv = zp[(size_t)s * 8 + lane];
      float f[8]; bf_dec8(vv, f);
      #pragma unroll
      for (int c = 0; c < 8; c++) acc[c] += a * f[c];
    }
    #pragma unroll
    for (int c = 0; c < 8; c++) hrow[c] += cinv * acc[c];
  }
  uint4 o;
  o.x = bf_pack(hrow[0], hrow[1]); o.y = bf_pack(hrow[2], hrow[3]);
  o.z = bf_pack(hrow[4], hrow[5]); o.w = bf_pack(hrow[6], hrow[7]);
  h2b[(size_t)d * 8 + lane] = o;
  float p[16];
  #pragma unroll
  for (int e2 = 0; e2 < 2; e2++) {
    #pragma unroll
    for (int h = 0; h < 4; h++) {
      const float* a = wlm + (e2 * 4 + h) * 64 + c0;
      const float* b = wrm + (e2 * 4 + h) * 64 + c0;
      float sl = 0.f, sr = 0.f;
      #pragma unroll
      for (int c = 0; c < 8; c++) { sl += hrow[c] * a[c]; sr += hrow[c] * b[c]; }
      p[e2*4+h] = sl; p[8+e2*4+h] = sr;
    }
  }
  #pragma unroll
  for (int off = 1; off < 8; off <<= 1) {
    #pragma unroll
    for (int i = 0; i < 16; i++) p[i] += __shfl_xor(p[i], off, 8);
  }
  if (lane == 0) *(float4*)(elm + (size_t)d * 4)        = make_float4(p[0], p[1], p[2], p[3]);
  if (lane == 1) *(float4*)(elm + ((size_t)NN + d) * 4) = make_float4(p[4], p[5], p[6], p[7]);
  if (lane == 2) *(float4*)(erm + (size_t)d * 4)        = make_float4(p[8], p[9], p[10], p[11]);
  if (lane == 3) *(float4*)(erm + ((size_t)NN + d) * 4) = make_float4(p[12], p[13], p[14], p[15]);
}

// ===== MH aggregation with inline softmax (alpha4_k fused away):
// u[(e*4+h)][d][0..63] = sum_j alpha[e][j][h] * h2b[cs[j]]; 8 lanes per dst.
__global__ __launch_bounds__(256) void agg_mh_k(
    const int* __restrict__ rowptr, const int* __restrict__ csr_src,
    const float* __restrict__ elm, const float* __restrict__ erm,
    const uint4* __restrict__ h2b, float* __restrict__ u) {
  int d = blockIdx.x * 32 + (threadIdx.x >> 3);
  int lane = threadIdx.x & 7, c0 = lane * 8;
  if (d >= NN) return;
  #pragma unroll
  for (int e = 0; e < 2; e++) {
    const int* rp = rowptr + e * 50001;
    const int* cs = csr_src + (size_t)e * EE;
    const float* elp = elm + (size_t)e * NN * 4;
    float4 er4 = *(const float4*)(erm + ((size_t)e * NN + d) * 4);
    int j0 = rp[d], j1 = rp[d + 1];
    // softmax denominators (strided over 8 lanes, then butterfly reduce)
    float4 sm = make_float4(0.f, 0.f, 0.f, 0.f);
    for (int j = j0 + lane; j < j1; j += 8) {
      float4 v = *(const float4*)(elp + (size_t)cs[j] * 4);
      sm.x += __expf(lrelu(v.x + er4.x));
      sm.y += __expf(lrelu(v.y + er4.y));
      sm.z += __expf(lrelu(v.z + er4.z));
      sm.w += __expf(lrelu(v.w + er4.w));
    }
    #pragma unroll
    for (int off = 1; off < 8; off <<= 1) {
      sm.x += __shfl_xor(sm.x, off, 8);
      sm.y += __shfl_xor(sm.y, off, 8);
      sm.z += __shfl_xor(sm.z, off, 8);
      sm.w += __shfl_xor(sm.w, off, 8);
    }
    float4 inv = make_float4(1.f / fmaxf(sm.x, 1e-9f), 1.f / fmaxf(sm.y, 1e-9f),
                             1.f / fmaxf(sm.z, 1e-9f), 1.f / fmaxf(sm.w, 1e-9f));
    float acc[4][8] = {};
    int j = j0;
    for (; j + 2 <= j1; j += 2) {
      int sA = cs[j], sB = cs[j+1];
      float4 vA = *(const float4*)(elp + (size_t)sA * 4);
      float4 vB = *(const float4*)(elp + (size_t)sB * 4);
      uint4 hA = h2b[(size_t)sA * 8 + lane];
      uint4 hB = h2b[(size_t)sB * 8 + lane];
      float4 wA, wB;
      wA.x = __expf(lrelu(vA.x + er4.x)) * inv.x;
      wA.y = __expf(lrelu(vA.y + er4.y)) * inv.y;
      wA.z = __expf(lrelu(vA.z + er4.z)) * inv.z;
      wA.w = __expf(lrelu(vA.w + er4.w)) * inv.w;
      wB.x = __expf(lrelu(vB.x + er4.x)) * inv.x;
      wB.y = __expf(lrelu(vB.y + er4.y)) * inv.y;
      wB.z = __expf(lrelu(vB.z + er4.z)) * inv.z;
      wB.w = __expf(lrelu(vB.w + er4.w)) * inv.w;
      float fA[8], fB[8];
      bf_dec8(hA, fA); bf_dec8(hB, fB);
      #pragma unroll
      for (int c = 0; c < 8; c++) {
        acc[0][c] += wA.x*fA[c] + wB.x*fB[c];
        acc[1][c] += wA.y*fA[c] + wB.y*fB[c];
        acc[2][c] += wA.z*fA[c] + wB.z*fB[c];
        acc[3][c] += wA.w*fA[c] + wB.w*fB[c];
      }
    }
    for (; j < j1; j++) {
      int s = cs[j];
      float4 v = *(const float4*)(elp + (size_t)s * 4);
      uint4 hh = h2b[(size_t)s * 8 + lane];
      float4 w;
      w.x = __expf(lrelu(v.x + er4.x)) * inv.x;
      w.y = __expf(lrelu(v.y + er4.y)) * inv.y;
      w.z = __expf(lrelu(v.z + er4.z)) * inv.z;
      w.w = __expf(lrelu(v.w + er4.w)) * inv.w;
      float f[8]; bf_dec8(hh, f);
      #pragma unroll
      for (int c = 0; c < 8; c++) {
        acc[0][c] += w.x*f[c]; acc[1][c] += w.y*f[c];
        acc[2][c] += w.z*f[c]; acc[3][c] += w.w*f[c];
      }
    }
    #pragma unroll
    for (int h = 0; h < 4; h++) {
      float* up = u + (((size_t)(e * 4 + h) * NN) + d) * 64 + c0;
      *(float4*)up       = make_float4(acc[h][0], acc[h][1], acc[h][2], acc[h][3]);
      *(float4*)(up + 4) = make_float4(acc[h][4], acc[h][5], acc[h][6], acc[h][7]);
    }
  }
}

// ===== column sums of u per (e,h) =====
__global__ __launch_bounds__(256) void colsum_u_k(
    const float* __restrict__ u, float* __restrict__ usum) {
  __shared__ float lds[4][64];
  int eh = blockIdx.x >> 6;
  int chunk = blockIdx.x & 63;
  int c = threadIdx.x & 63, rg = threadIdx.x >> 6;
  const float* up = u + (size_t)eh * NN * 64;
  int n0 = chunk * 782;
  int n1 = n0 + 782; if (n1 > NN) n1 = NN;
  float s = 0.f;
  for (int n = n0 + rg; n < n1; n += 4) s += up[(size_t)n * 64 + c];
  lds[rg][c] = s;
  __syncthreads();
  if (rg == 0) {
    float t = lds[0][c] + lds[1][c] + lds[2][c] + lds[3][c];
    unsafeAtomicAdd(&usum[eh * 64 + c], t);
  }
}

__global__ __launch_bounds__(256) void mean_k(
    const float* __restrict__ usum, const float* __restrict__ Wm,
    float* __restrict__ mean) {
  int c = threadIdx.x;
  int h = c >> 6;
  float s = 0.f;
  for (int e = 0; e < 2; e++) {
    const float* us = usum + (e * 4 + h) * 64;
    const float* wp = Wm + (size_t)e * 64 * 256 + c;
    for (int k = 0; k < 64; k++) s += us[k] * wp[(size_t)k * 256];
  }
  mean[c] = s * (0.5f / NN);
}

// out[d][h*64+f] = 0.5*sum_e u[(e*4+h)][d][:]@Wm[e][:,h*64+f] - mean[c]
__global__ __launch_bounds__(256) void out_gemm_k(
    const float* __restrict__ u, const float* __restrict__ Wm,
    const float* __restrict__ mean, float* __restrict__ out) {
  __shared__ float As[16][132];
  __shared__ float Bs[16][68];
  const int h = blockIdx.y;
  const int tid = threadIdx.x;
  const int tx = tid & 15, ty = tid >> 4;
  const int row0 = blockIdx.x * 128;
  float acc[2][16] = {};
  for (int e = 0; e < 2; e++) {
    const float* Up = u + (size_t)(e * 4 + h) * NN * 64;
    const float* Wp = Wm + (size_t)e * 64 * 256 + h * 64;
    for (int k0 = 0; k0 < 64; k0 += 16) {
      #pragma unroll
      for (int i = 0; i < 2; i++) {
        int t = tid + i * 256;
        int r = t >> 2, cv = t & 3;
        int rr = row0 + r; if (rr >= NN) rr = NN - 1;
        float4 v = *(const float4*)(Up + (size_t)rr * 64 + k0 + cv * 4);
        As[cv*4+0][r] = v.x; As[cv*4+1][r] = v.y;
        As[cv*4+2][r] = v.z; As[cv*4+3][r] = v.w;
      }
      {
        int r = tid >> 4, c = tid & 15;
        *(float4*)&Bs[r][c*4] = *(const float4*)(Wp + (size_t)(k0 + r) * 256 + c * 4);
      }
      __syncthreads();
      #pragma unroll
      for (int kk = 0; kk < 16; kk++) {
        float4 a0 = *(const float4*)&As[kk][ty*4];
        float4 a1 = *(const float4*)&As[kk][64 + ty*4];
        float4 bv = *(const float4*)&Bs[kk][tx*4];
        float* ac = acc[0];
        ac[0]  += a0.x*bv.x; ac[1]  += a0.x*bv.y; ac[2]  += a0.x*bv.z; ac[3]  += a0.x*bv.w;
        ac[4]  += a0.y*bv.x; ac[5]  += a0.y*bv.y; ac[6]  += a0.y*bv.z; ac[7]  += a0.y*bv.w;
        ac[8]  += a0.z*bv.x; ac[9]  += a0.z*bv.y; ac[10] += a0.z*bv.z; ac[11] += a0.z*bv.w;
        ac[12] += a0.w*bv.x; ac[13] += a0.w*bv.y; ac[14] += a0.w*bv.z; ac[15] += a0.w*bv.w;
        ac = acc[1];
        ac[0]  += a1.x*bv.x; ac[1]  += a1.x*bv.y; ac[2]  += a1.x*bv.z; ac[3]  += a1.x*bv.w;
        ac[4]  += a1.y*bv.x; ac[5]  += a1.y*bv.y; ac[6]  += a1.y*bv.z; ac[7]  += a1.y*bv.w;
        ac[8]  += a1.z*bv.x; ac[9]  += a1.z*bv.y; ac[10] += a1.z*bv.z; ac[11] += a1.z*bv.w;
        ac[12] += a1.w*bv.x; ac[13] += a1.w*bv.y; ac[14] += a1.w*bv.z; ac[15] += a1.w*bv.w;
      }
      __syncthreads();
    }
  }
  float4 mn = *(const float4*)(mean + h * 64 + tx * 4);
  #pragma unroll
  for (int rp = 0; rp < 2; rp++) {
    #pragma unroll
    for (int i = 0; i < 4; i++) {
      int r = row0 + rp*64 + ty*4 + i;
      if (r < NN) {
        float* ac = acc[rp];
        *(float4*)(out + (size_t)r * 256 + h * 64 + tx * 4) =
            make_float4(0.5f*ac[i*4+0] - mn.x, 0.5f*ac[i*4+1] - mn.y,
                        0.5f*ac[i*4+2] - mn.z, 0.5f*ac[i*4+3] - mn.w);
      }
    }
  }
}

// ================= host-side launch =================
extern "C" void kernel_launch(void* const* d_in, const int* in_sizes, int n_in,
                              void* d_out, int out_size, void* d_ws, size_t ws_size,
                              hipStream_t stream) {
  const float* x  = (const float*)d_in[0];
  const int* src0 = (const int*)d_in[1];
  const int* dst0 = (const int*)d_in[2];
  const int* src1 = (const int*)d_in[3];
  const int* dst1 = (const int*)d_in[4];
  const float* W1  = (const float*)d_in[5];
  const float* al1 = (const float*)d_in[6];
  const float* ar1 = (const float*)d_in[7];
  const float* b1  = (const float*)d_in[8];
  const float* W2  = (const float*)d_in[9];
  const float* al2 = (const float*)d_in[10];
  const float* ar2 = (const float*)d_in[11];
  const float* b2  = (const float*)d_in[12];
  const float* Wm  = (const float*)d_in[13];
  const float* alm = (const float*)d_in[14];
  const float* arm = (const float*)d_in[15];
  // d_in[16] = bm: cancels under per-head mean-centering
  const float* fcw = (const float*)d_in[17];
  float* out = (float*)d_out;

  float* ws = (float*)d_ws;
  float* zu     = ws;                                  // u1 fp32 12.8M / u 25.6M
  unsigned int* z2b = (unsigned int*)(ws + 12800000);  // bf16 z2, 3.2M uints
  float* h1     = ws + 25600000;   // 6.4M; aliases xb early
  unsigned int* xb = (unsigned int*)h1;
  unsigned int* h2b = (unsigned int*)(ws + 32000000);  // 1.6M uints
  float* el     = ws + 33600000;   // 0.4M
  float* er     = ws + 34000000;   // 0.4M
  float* elm    = ws + 34400000;   // 0.4M
  float* erm    = ws + 34800000;   // 0.4M
  float* wl1    = ws + 35200000;
  float* wr1    = wl1 + 256;
  float* wl2    = wr1 + 256;
  float* wr2    = wl2 + 256;
  float* wlm    = wr2 + 256;
  float* wrm    = wlm + 512;
  float* usum   = wrm + 512;
  float* meanp  = usum + 512;
  int* rowptr  = (int*)(meanp + 256);          // 2*50001
  int* csr_src = rowptr + 100002;              // 2*EE
  int* deg    = (int*)el;
  int* inc    = (int*)er;
  int* cursor = (int*)zu;
  int* bsum   = (int*)zu + 200000;

  hipMemsetAsync(deg, 0, 2 * 50000 * sizeof(int), stream);
  hipMemsetAsync(usum, 0, 512 * sizeof(float), stream);
  deg2_k<<<6250, 256, 0, stream>>>(dst0, dst1, deg);
  scan1_k<<<dim3(98, 2), 512, 0, stream>>>(deg, inc, bsum);
  scan2_k<<<2, 128, 0, stream>>>(bsum, 98);
  scan3_k<<<dim3(196, 2), 256, 0, stream>>>(deg, inc, bsum, rowptr, cursor);
  csr_scatter2_k<<<8 * SC_BPR, 256, 0, stream>>>(src0, dst0, src1, dst1,
                                                 cursor, csr_src);

  fold_k<<<8, 256, 0, stream>>>(W1, al1, ar1, W2, al2, ar2, Wm, alm, arm,
                                wl1, wr1, wl2, wr2, wlm, wrm);
  xcast_k<<<12500, 256, 0, stream>>>(x, xb);

  // ================= layer 1 =================
  dot2_k<<<3125, 256, 0, stream>>>(x, wl1, wr1, el, er);
  agg_x_f<<<3125, 256, 0, stream>>>(rowptr, csr_src, el, er, (const uint4*)xb, zu);
  ugemm1_k<<<391, 256, 0, stream>>>(zu, W1, b1, h1);

  // ================= layer 2 =================
  dot2_k<<<3125, 256, 0, stream>>>(h1, wl2, wr2, el, er);
  gemm64_k<<<dim3(391, 1, 2), 256, 0, stream>>>(h1, W2, z2b);
  agg2_f<<<1563, 256, 0, stream>>>(rowptr, csr_src, el, er, (const uint4*)z2b,
                                   b2, fcw, wlm, wrm, (uint4*)h2b, elm, erm);

  // ================= MH layer =================
  agg_mh_k<<<1563, 256, 0, stream>>>(rowptr, csr_src, elm, erm,
                                     (const uint4*)h2b, zu);
  colsum_u_k<<<512, 256, 0, stream>>>(zu, usum);
  mean_k<<<1, 256, 0, stream>>>(usum, Wm, meanp);
  out_gemm_k<<<dim3(391, 4), 256, 0, stream>>>(zu, Wm, meanp, out);
}